// Round 1
// baseline (348.352 us; speedup 1.0000x reference)
//
#include <hip/hip_runtime.h>

#define BB 256
#define NP 12
#define TT 20
#define DD 512
#define EPS_A 1e-6f
#define EPS_BN 1e-5f
#define THR2 (150.0f * 150.0f)

// ---------------------------------------------------------------------------
// Adjacency: per batch, A[n][k] = (d2 < 150^2), AT[j][n] = A[n][j]/(rowsum(n)+eps)
// ---------------------------------------------------------------------------
__global__ void adj_kernel(const float* __restrict__ bboxes, float* __restrict__ AT) {
    int b = blockIdx.x;
    int t = threadIdx.x;
    __shared__ float cx[NP], cy[NP];
    __shared__ float A[NP][NP];
    __shared__ float rinv[NP];
    if (t < NP) {
        const float* p = bboxes + (b * NP + t) * 4;
        cx[t] = p[0] + 0.5f * p[2];
        cy[t] = p[1] + 0.5f * p[3];
    }
    __syncthreads();
    for (int idx = t; idx < NP * NP; idx += 64) {
        int n = idx / NP, k = idx % NP;
        float dx = cx[n] - cx[k], dy = cy[n] - cy[k];
        A[n][k] = (dx * dx + dy * dy < THR2) ? 1.0f : 0.0f;
    }
    __syncthreads();
    if (t < NP) {
        float s = 0.f;
        #pragma unroll
        for (int k = 0; k < NP; k++) s += A[t][k];
        rinv[t] = 1.0f / (s + EPS_A);
    }
    __syncthreads();
    for (int idx = t; idx < NP * NP; idx += 64) {
        int j = idx / NP, n = idx % NP;
        AT[(b * NP + j) * NP + n] = A[n][j] * rinv[n];
    }
}

// ---------------------------------------------------------------------------
// 512x512 transpose: Wt[c][d] = W[d][c]
// ---------------------------------------------------------------------------
__global__ void transpose_kernel(const float* __restrict__ Win, float* __restrict__ Wt) {
    __shared__ float tile[32][33];
    int x = blockIdx.x * 32 + threadIdx.x;  // c
    int y = blockIdx.y * 32 + threadIdx.y;  // d
    #pragma unroll
    for (int i = 0; i < 32; i += 8)
        tile[threadIdx.y + i][threadIdx.x] = Win[(y + i) * DD + x];
    __syncthreads();
    int xo = blockIdx.y * 32 + threadIdx.x;  // d
    int yo = blockIdx.x * 32 + threadIdx.y;  // c
    #pragma unroll
    for (int i = 0; i < 32; i += 8)
        Wt[(yo + i) * DD + xo] = tile[threadIdx.x][threadIdx.y + i];
}

// ---------------------------------------------------------------------------
// Full-tensor float4 copy (last-timestep slice gets overwritten by layer 2)
// ---------------------------------------------------------------------------
__global__ void copy_kernel(const float4* __restrict__ in, float4* __restrict__ out, int n4) {
    int i = blockIdx.x * blockDim.x + threadIdx.x;
    if (i < n4) out[i] = in[i];
}

// ---------------------------------------------------------------------------
// One ST-GCN layer for one batch x 256-column slice.
//   xg[j][c] = sum_n AT[j][n] * x[n][c]          (LDS)
//   out[j][d] = relu( (sum_c xg[j][c]*Wt[c][d]) * s[d] + t[d] )
// LAYER==1: x from pf[:, :, 19, :], out -> y1 (B,12,512)
// LAYER==2: x from y1,              out -> d_out[:, :, 19, :]
// ---------------------------------------------------------------------------
template <int LAYER>
__global__ __launch_bounds__(256) void layer_kernel(
    const float* __restrict__ xin, const float* __restrict__ AT,
    const float* __restrict__ Wt, const float* __restrict__ bias,
    const float* __restrict__ g, const float* __restrict__ beta,
    const float* __restrict__ m, const float* __restrict__ v,
    float* __restrict__ out) {
    int b = blockIdx.y;
    int slice = blockIdx.x;  // 0..1
    int t = threadIdx.x;     // 0..255

    __shared__ float xs[NP][DD];   // 24 KB
    __shared__ float xg[NP][DD];   // 24 KB
    __shared__ float at[NP][NP];

    if (t < NP * NP) at[t / NP][t % NP] = AT[b * NP * NP + t];

    // stage x (12 x 512) -- coalesced
    for (int i = t; i < NP * DD; i += 256) {
        int n = i >> 9, c = i & (DD - 1);
        float val;
        if (LAYER == 1)
            val = xin[((long)(b * NP + n) * TT + (TT - 1)) * DD + c];
        else
            val = xin[(long)(b * NP + n) * DD + c];
        xs[n][c] = val;
    }
    __syncthreads();

    // graph mix: each thread owns 2 columns c
    for (int c = t; c < DD; c += 256) {
        float acc[NP];
        #pragma unroll
        for (int j = 0; j < NP; j++) acc[j] = 0.f;
        #pragma unroll
        for (int n = 0; n < NP; n++) {
            float xv = xs[n][c];
            #pragma unroll
            for (int j = 0; j < NP; j++) acc[j] += at[j][n] * xv;
        }
        #pragma unroll
        for (int j = 0; j < NP; j++) xg[j][c] = acc[j];
    }
    __syncthreads();

    // GEMM: this thread owns output column d for all 12 rows
    int d = slice * 256 + t;
    float acc[NP];
    #pragma unroll
    for (int j = 0; j < NP; j++) acc[j] = 0.f;

    for (int c = 0; c < DD; c += 4) {
        float w0 = Wt[(c + 0) * DD + d];
        float w1 = Wt[(c + 1) * DD + d];
        float w2 = Wt[(c + 2) * DD + d];
        float w3 = Wt[(c + 3) * DD + d];
        #pragma unroll
        for (int j = 0; j < NP; j++) {
            float4 x4 = *(const float4*)&xg[j][c];
            acc[j] += x4.x * w0 + x4.y * w1 + x4.z * w2 + x4.w * w3;
        }
    }

    float s = g[d] * rsqrtf(v[d] + EPS_BN);
    float tadd = (bias[d] - m[d]) * s + beta[d];
    #pragma unroll
    for (int j = 0; j < NP; j++) {
        float y = fmaxf(acc[j] * s + tadd, 0.f);
        if (LAYER == 1)
            out[(long)(b * NP + j) * DD + d] = y;
        else
            out[((long)(b * NP + j) * TT + (TT - 1)) * DD + d] = y;
    }
}

// ---------------------------------------------------------------------------
extern "C" void kernel_launch(void* const* d_in, const int* in_sizes, int n_in,
                              void* d_out, int out_size, void* d_ws, size_t ws_size,
                              hipStream_t stream) {
    const float* pf = (const float*)d_in[0];
    const float* bboxes = (const float*)d_in[1];
    const float* W1 = (const float*)d_in[2];
    const float* b1 = (const float*)d_in[3];
    const float* g1 = (const float*)d_in[4];
    const float* beta1 = (const float*)d_in[5];
    const float* m1 = (const float*)d_in[6];
    const float* v1 = (const float*)d_in[7];
    const float* W2 = (const float*)d_in[8];
    const float* b2 = (const float*)d_in[9];
    const float* g2 = (const float*)d_in[10];
    const float* beta2 = (const float*)d_in[11];
    const float* m2 = (const float*)d_in[12];
    const float* v2 = (const float*)d_in[13];
    float* out = (float*)d_out;

    float* ws = (float*)d_ws;
    float* atp = ws;                  // 256*144 = 36864 floats
    float* wt1 = atp + 36864;         // 262144 floats
    float* wt2 = wt1 + 262144;        // 262144 floats
    float* y1 = wt2 + 262144;         // 1572864 floats

    adj_kernel<<<BB, 64, 0, stream>>>(bboxes, atp);
    dim3 tb(32, 8);
    transpose_kernel<<<dim3(16, 16), tb, 0, stream>>>(W1, wt1);
    transpose_kernel<<<dim3(16, 16), tb, 0, stream>>>(W2, wt2);

    int n4 = (BB * NP * TT * DD) / 4;  // 7864320
    copy_kernel<<<n4 / 256, 256, 0, stream>>>((const float4*)pf, (float4*)out, n4);

    layer_kernel<1><<<dim3(2, BB), 256, 0, stream>>>(pf, atp, wt1, b1, g1, beta1, m1, v1, y1);
    layer_kernel<2><<<dim3(2, BB), 256, 0, stream>>>(y1, atp, wt2, b2, g2, beta2, m2, v2, out);
}

// Round 2
// 269.714 us; speedup vs baseline: 1.2916x; 1.2916x over previous
//
#include <hip/hip_runtime.h>

#define BB 256
#define NP 12
#define TT 20
#define DD 512
#define EPS_A 1e-6f
#define EPS_BN 1e-5f
#define THR2 (150.0f * 150.0f)
#define MROWS (BB * NP)   // 3072
#define PITCH 40          // LDS row pitch in ushorts (80 B: 16B-aligned, <=2-way bank alias)

typedef __attribute__((ext_vector_type(8))) short shortx8;
typedef __attribute__((ext_vector_type(4))) float floatx4;

static __device__ __forceinline__ ushort f2bf(float f) {
    unsigned x = __float_as_uint(f);
    return (ushort)((x + 0x7fffu + ((x >> 16) & 1u)) >> 16);  // RNE
}

// grid-stride copy of float4 range [lo,hi); skip==true skips t==19 rows (gemm2 writes them)
static __device__ __forceinline__ void copy_body(int cb, int ncb, long lo, long hi,
                                                 const float4* __restrict__ src,
                                                 float4* __restrict__ dst, bool skip) {
    long stride = (long)ncb * 256;
    for (long g = lo + (long)cb * 256 + threadIdx.x; g < hi; g += stride) {
        if (skip) {
            int row = (int)(g >> 7);           // 128 float4 per 512-float row
            if (row % TT == TT - 1) continue;  // slice row: written by gemm2
        }
        dst[g] = src[g];
    }
}

// ---------------------------------------------------------------------------
// K1: [0,256) adjacency + mix1 (pf last slice -> xg1 bf16)
//     [256,320) cast W1,W2 -> bf16 ; [320] BN scale/shift vecs ; rest copy
// ---------------------------------------------------------------------------
__global__ __launch_bounds__(256) void k1_prep(
    const float* __restrict__ pf, const float* __restrict__ bboxes,
    const float* __restrict__ W1, const float* __restrict__ W2,
    const float* __restrict__ b1, const float* __restrict__ g1,
    const float* __restrict__ beta1, const float* __restrict__ m1, const float* __restrict__ v1,
    const float* __restrict__ b2, const float* __restrict__ g2,
    const float* __restrict__ beta2, const float* __restrict__ m2, const float* __restrict__ v2,
    float* __restrict__ atg, float* __restrict__ s1, float* __restrict__ t1,
    float* __restrict__ s2, float* __restrict__ t2,
    ushort* __restrict__ wb1, ushort* __restrict__ wb2, ushort* __restrict__ xg1,
    const float4* __restrict__ csrc, float4* __restrict__ cdst) {
    int bid = blockIdx.x, t = threadIdx.x;
    if (bid < BB) {
        int b = bid;
        __shared__ float cx[NP], cy[NP], Ash[NP][NP], rinv[NP], at[NP][NP];
        if (t < NP) {
            const float* p = bboxes + (b * NP + t) * 4;
            cx[t] = p[0] + 0.5f * p[2];
            cy[t] = p[1] + 0.5f * p[3];
        }
        __syncthreads();
        if (t < NP * NP) {
            int n = t / NP, k = t % NP;
            float dx = cx[n] - cx[k], dy = cy[n] - cy[k];
            Ash[n][k] = (dx * dx + dy * dy < THR2) ? 1.f : 0.f;
        }
        __syncthreads();
        if (t < NP) {
            float s = 0.f;
            #pragma unroll
            for (int k = 0; k < NP; k++) s += Ash[t][k];
            rinv[t] = 1.f / (s + EPS_A);
        }
        __syncthreads();
        if (t < NP * NP) {
            int j = t / NP, n = t % NP;
            float val = Ash[n][j] * rinv[n];
            at[j][n] = val;
            atg[b * NP * NP + t] = val;
        }
        __syncthreads();
        for (int c = t; c < DD; c += 256) {
            float xv[NP];
            #pragma unroll
            for (int n = 0; n < NP; n++)
                xv[n] = pf[((long)((b * NP + n) * TT + TT - 1)) * DD + c];
            #pragma unroll
            for (int j = 0; j < NP; j++) {
                float a = 0.f;
                #pragma unroll
                for (int n = 0; n < NP; n++) a += at[j][n] * xv[n];
                xg1[(long)(b * NP + j) * DD + c] = f2bf(a);
            }
        }
    } else if (bid < 320) {  // W cast: 131072 float4 total (W1 then W2)
        int idx = (bid - 256) * 256 + t;
        for (int i = idx; i < 131072; i += 16384) {
            float4 f = (i < 65536) ? ((const float4*)W1)[i] : ((const float4*)W2)[i - 65536];
            ushort4 u;
            u.x = f2bf(f.x); u.y = f2bf(f.y); u.z = f2bf(f.z); u.w = f2bf(f.w);
            if (i < 65536) *(ushort4*)(wb1 + (long)i * 4) = u;
            else           *(ushort4*)(wb2 + (long)(i - 65536) * 4) = u;
        }
    } else if (bid == 320) {
        for (int d = t; d < DD; d += 256) {
            float sa = g1[d] * rsqrtf(v1[d] + EPS_BN);
            s1[d] = sa; t1[d] = (b1[d] - m1[d]) * sa + beta1[d];
            float sb = g2[d] * rsqrtf(v2[d] + EPS_BN);
            s2[d] = sb; t2[d] = (b2[d] - m2[d]) * sb + beta2[d];
        }
    } else {
        copy_body(bid - 321, 256, 0L, 524288L, csrc, cdst, false);
    }
}

// ---------------------------------------------------------------------------
// MFMA GEMM: C[m,d] = relu( (sum_c xg_bf16[m,c]*W_bf16[d,c]) * s[d] + t[d] )
// Block: 64m x 64n tile, 4 waves (wave = 16m x 64n), BK=32, 16 k-iters.
// LAYER 1 -> y1 (3072,512) fp32 ; LAYER 2 -> d_out slice rows (m*20+19).
// ---------------------------------------------------------------------------
template <int LAYER>
static __device__ void gemm_body(int bid, int t,
                                 const ushort* __restrict__ xg, const ushort* __restrict__ wb,
                                 const float* __restrict__ sv, const float* __restrict__ tv,
                                 float* __restrict__ out) {
    __shared__ __align__(16) ushort Alds[64 * PITCH];
    __shared__ __align__(16) ushort Blds[64 * PITCH];
    int m0 = (bid >> 3) * 64;
    int n0 = (bid & 7) * 64;
    int wave = t >> 6, lane = t & 63;
    int quad = lane >> 4, mrow = lane & 15;
    int r = t >> 2, seg = t & 3;  // staging: 4 threads x 16B per 64B row-chunk

    floatx4 acc[4] = {{0, 0, 0, 0}, {0, 0, 0, 0}, {0, 0, 0, 0}, {0, 0, 0, 0}};

    const uint4* gA = (const uint4*)(xg + (long)(m0 + r) * DD + seg * 8);
    const uint4* gB = (const uint4*)(wb + (long)(n0 + r) * DD + seg * 8);
    uint4* lA = (uint4*)&Alds[r * PITCH + seg * 8];
    uint4* lB = (uint4*)&Blds[r * PITCH + seg * 8];
    const ushort* ra = &Alds[(wave * 16 + mrow) * PITCH + quad * 8];
    const ushort* rb = &Blds[mrow * PITCH + quad * 8];

    for (int kc = 0; kc < DD; kc += 32) {
        uint4 av = gA[kc >> 3];  // kc/8 uint4 = kc ushorts
        uint4 bv = gB[kc >> 3];
        __syncthreads();  // guard prior-iter LDS reads
        *lA = av;
        *lB = bv;
        __syncthreads();
        shortx8 af = *(const shortx8*)ra;
        #pragma unroll
        for (int nt = 0; nt < 4; nt++) {
            shortx8 bf = *(const shortx8*)(rb + nt * 16 * PITCH);
            acc[nt] = __builtin_amdgcn_mfma_f32_16x16x32_bf16(af, bf, acc[nt], 0, 0, 0);
        }
    }

    #pragma unroll
    for (int nt = 0; nt < 4; nt++) {
        int d = n0 + nt * 16 + mrow;
        float s = sv[d], tt = tv[d];
        #pragma unroll
        for (int v = 0; v < 4; v++) {
            int m = m0 + wave * 16 + quad * 4 + v;
            float val = fmaxf(acc[nt][v] * s + tt, 0.f);
            if (LAYER == 1) out[(long)m * DD + d] = val;
            else            out[((long)m * TT + (TT - 1)) * DD + d] = val;
        }
    }
}

template <int LAYER>
__global__ __launch_bounds__(256) void k_gemm(
    const ushort* __restrict__ xg, const ushort* __restrict__ wb,
    const float* __restrict__ sv, const float* __restrict__ tv, float* __restrict__ out,
    const float4* __restrict__ csrc, float4* __restrict__ cdst,
    long clo, long chi, int skip) {
    int bid = blockIdx.x;
    if (bid < 384) gemm_body<LAYER>(bid, threadIdx.x, xg, wb, sv, tv, out);
    else copy_body(bid - 384, 832, clo, chi, csrc, cdst, skip != 0);
}

// ---------------------------------------------------------------------------
// K3: [0,256) mix2 (y1 fp32 -> xg2 bf16), rest copy
// ---------------------------------------------------------------------------
__global__ __launch_bounds__(256) void k3_mix2(
    const float* __restrict__ y1v, const float* __restrict__ atg, ushort* __restrict__ xg2,
    const float4* __restrict__ csrc, float4* __restrict__ cdst) {
    int bid = blockIdx.x, t = threadIdx.x;
    if (bid < BB) {
        __shared__ float at[NP * NP];
        if (t < NP * NP) at[t] = atg[bid * NP * NP + t];
        __syncthreads();
        for (int c = t; c < DD; c += 256) {
            float xv[NP];
            #pragma unroll
            for (int n = 0; n < NP; n++) xv[n] = y1v[(long)(bid * NP + n) * DD + c];
            #pragma unroll
            for (int j = 0; j < NP; j++) {
                float a = 0.f;
                #pragma unroll
                for (int n = 0; n < NP; n++) a += at[j * NP + n] * xv[n];
                xg2[(long)(bid * NP + j) * DD + c] = f2bf(a);
            }
        }
    } else {
        copy_body(bid - 256, 256, 3932160L, 4456448L, csrc, cdst, false);
    }
}

// ---------------------------------------------------------------------------
extern "C" void kernel_launch(void* const* d_in, const int* in_sizes, int n_in,
                              void* d_out, int out_size, void* d_ws, size_t ws_size,
                              hipStream_t stream) {
    const float* pf = (const float*)d_in[0];
    const float* bboxes = (const float*)d_in[1];
    const float* W1 = (const float*)d_in[2];
    const float* b1 = (const float*)d_in[3];
    const float* g1 = (const float*)d_in[4];
    const float* beta1 = (const float*)d_in[5];
    const float* m1 = (const float*)d_in[6];
    const float* v1 = (const float*)d_in[7];
    const float* W2 = (const float*)d_in[8];
    const float* b2 = (const float*)d_in[9];
    const float* g2 = (const float*)d_in[10];
    const float* beta2 = (const float*)d_in[11];
    const float* m2 = (const float*)d_in[12];
    const float* v2 = (const float*)d_in[13];
    float* out = (float*)d_out;

    float* ws = (float*)d_ws;
    float* atg = ws;                          // 36864 f
    float* s1 = ws + 36864;
    float* t1v = s1 + 512;
    float* s2 = t1v + 512;
    float* t2v = s2 + 512;
    ushort* wb1 = (ushort*)(t2v + 512);       // 262144 us
    ushort* wb2 = wb1 + 262144;               // 262144 us
    ushort* xg1 = wb2 + 262144;               // 1572864 us
    ushort* xg2 = xg1 + (long)MROWS * DD;     // 1572864 us
    float* y1v = (float*)(xg2 + (long)MROWS * DD);  // 1572864 f

    const float4* csrc = (const float4*)pf;
    float4* cdst = (float4*)out;
    // copy split (float4 units, total 7864320): K1 [0,524288) K2 [524288,3932160)
    // K3 [3932160,4456448) K4 [4456448,7864320) (K4 skips t==19 rows; gemm2 writes them)

    k1_prep<<<577, 256, 0, stream>>>(pf, bboxes, W1, W2, b1, g1, beta1, m1, v1,
                                     b2, g2, beta2, m2, v2, atg, s1, t1v, s2, t2v,
                                     wb1, wb2, xg1, csrc, cdst);
    k_gemm<1><<<1216, 256, 0, stream>>>(xg1, wb1, s1, t1v, y1v, csrc, cdst,
                                        524288L, 3932160L, 0);
    k3_mix2<<<512, 256, 0, stream>>>(y1v, atg, xg2, csrc, cdst);
    k_gemm<2><<<1216, 256, 0, stream>>>(xg2, wb2, s2, t2v, out, csrc, cdst,
                                        4456448L, 7864320L, 1);
}